// Round 5
// baseline (400.887 us; speedup 1.0000x reference)
//
#include <hip/hip_runtime.h>

// Problem constants
#define B_DIM 8
#define NPTS  81920
#define DTOT  20          // DL + DA
#define DT_STEP 0.1f

#define BLOCK 256
#define GRID  1280
#define ITERS 8           // GRID/8 * ITERS * 64 = 81920 points per batch
#define MROW  40          // mirror row bytes (20 bf16)

typedef __attribute__((ext_vector_type(8))) short short8;   // 8 bf16 (4 VGPRs)
typedef __attribute__((ext_vector_type(4))) float f32x4;    // MFMA acc / NT-able vec
typedef __attribute__((ext_vector_type(2))) unsigned u32x2; // NT-able 8B vec
typedef __attribute__((ext_vector_type(4))) unsigned u32x4; // 16B dword glue

// ---- LDS ----
// phase 0: W1T [0,18432): 128 rows x 72 shorts (k=60 holds b1, 61..63 zero)
//          W2T [18432,22784): 16 rows x 136 shorts (pre-scaled by DT)
// loop:    h   [0,17408): per-wave 16 x 136 shorts (272 B rows) — wave-private
#define W2T_BASE 18432
#define SMEM_BYTES 22784

__device__ __forceinline__ unsigned short f2bf(float f) {
    unsigned u = __builtin_bit_cast(unsigned, f);
    u += 0x7FFFu + ((u >> 16) & 1u);           // RNE
    return (unsigned short)(u >> 16);
}
__device__ __forceinline__ unsigned pack2(float a, float b) {
    return (unsigned)f2bf(a) | ((unsigned)f2bf(b) << 16);
}
__device__ __forceinline__ float tanh_fast(float x) {
    float e = __builtin_amdgcn_exp2f(x * -2.885390082f);   // e^-2x
    e = fminf(e, 1e30f);
    float r = __builtin_amdgcn_rcpf(1.0f + e);
    return (1.0f - e) * r;
}
// select an 8B piece of the 120B concat of 3 mirror rows (o multiple of 8, o<120)
__device__ __forceinline__ u32x2 ldpiece(const char* r0, const char* r1,
                                         const char* r2, int o) {
    const char* p = r0 + o;
    if (o >= 40) p = r1 + (o - 40);
    if (o >= 80) p = r2 + (o - 80);
    return *(const u32x2*)p;
}

__global__ __launch_bounds__(BLOCK, 3) void neural_step_mfma(
    const float* __restrict__ Yin, float* __restrict__ Yout,
    const unsigned short* __restrict__ Min,   // bf16 mirror of Yin
    unsigned short* __restrict__ Mout,        // bf16 mirror of Yout (written here)
    const int*   __restrict__ nbr,
    const float* __restrict__ W1, const float* __restrict__ b1,
    const float* __restrict__ W2, const float* __restrict__ b2)
{
    __shared__ __align__(16) char smem[SMEM_BYTES];
    const int t = threadIdx.x;

    // ---- phase 0: stage W1^T (+b1 fold) and DT*W2^T as bf16 ----
    unsigned short* sW1T = (unsigned short*)smem;
    for (int f = t; f < 60 * 128; f += BLOCK) {      // W1[k][n] -> sW1T[n][k]
        int k = f >> 7, n = f & 127;
        sW1T[n * 72 + k] = f2bf(W1[f]);
    }
    if (t < 128) {                                    // bias fold at k=60; pad 61..63
        sW1T[t * 72 + 60] = f2bf(b1[t]);
        sW1T[t * 72 + 61] = 0; sW1T[t * 72 + 62] = 0; sW1T[t * 72 + 63] = 0;
    }
    unsigned short* sW2T = (unsigned short*)(smem + W2T_BASE);
    for (int f = t; f < 128 * 16; f += BLOCK) {      // DT*W2[k][d] -> sW2T[d][k]
        int k = f >> 4, d = f & 15;
        sW2T[d * 136 + k] = f2bf(DT_STEP * W2[f]);
    }
    __syncthreads();

    const int lane = t & 63, w = t >> 6;
    const int l15 = lane & 15, q = lane >> 4;

    // W1 A-fragments: A[m=hidden nt*16+l15][k=ks*32+q*8+j]
    short8 B1f[8][2];
    #pragma unroll
    for (int nt = 0; nt < 8; nt++)
        #pragma unroll
        for (int ks = 0; ks < 2; ks++)
            B1f[nt][ks] = *(const short8*)(sW1T + (nt * 16 + l15) * 72 + ks * 32 + q * 8);
    // W2^T A-fragments: A[d=l15][k=ks*32+q*8+j]
    short8 W2f[4];
    #pragma unroll
    for (int ks = 0; ks < 4; ks++)
        W2f[ks] = *(const short8*)(sW2T + l15 * 136 + ks * 32 + q * 8);
    const float b2a = b2[q * 4 + 0], b2b = b2[q * 4 + 1];
    const float b2c = b2[q * 4 + 2], b2d = b2[q * 4 + 3];
    const f32x4 acc2init = { DT_STEP * b2a, DT_STEP * b2b,
                             DT_STEP * b2c, DT_STEP * b2d };
    __syncthreads();   // weights in regs; LDS region reused for h tiles

    // ---- batch-per-XCD swizzle ----
    const int bk = blockIdx.x;
    const int bB = bk & 7;
    const int p0 = (bk >> 3) * (ITERS * 64) + w * 16 + l15;  // this lane's point, +it*64
    const char*  MinB  = (const char*)Min + (size_t)bB * NPTS * MROW;
    char*        MoutB = (char*)Mout      + (size_t)bB * NPTS * MROW;
    const size_t rowBase = (size_t)bB * NPTS;

    unsigned short* hrow = (unsigned short*)(smem + w * 4352);

    // per-lane concat offsets for the 4 gather pieces (8B each)
    const int o0 = q * 16, o1 = o0 + 8, o2 = 64 + q * 16, o3 = o2 + 8;  // o3==120 iff q==3
    const u32x2 biasPiece = { 0x00003F80u, 0u };                        // bf16 {1,0,0,0}

    // ---- software pipeline: nbr idx 2 ahead, gather 1 ahead ----
    int nx0, nx1, nx2, ny0 = 0, ny1 = 0, ny2 = 0;
    u32x2 gc0, gc1, gc2, gc3, gn0 = {0,0}, gn1 = {0,0}, gn2 = {0,0}, gn3 = {0,0};
    {
        const int* np = nbr + (size_t)p0 * 3;
        nx0 = __builtin_nontemporal_load(np);
        nx1 = __builtin_nontemporal_load(np + 1);
        nx2 = __builtin_nontemporal_load(np + 2);
        const char* r0 = MinB + (size_t)nx0 * MROW;
        const char* r1 = MinB + (size_t)nx1 * MROW;
        const char* r2 = MinB + (size_t)nx2 * MROW;
        gc0 = ldpiece(r0, r1, r2, o0);
        gc1 = ldpiece(r0, r1, r2, o1);
        gc2 = ldpiece(r0, r1, r2, o2);
        gc3 = (o3 < 120) ? ldpiece(r0, r1, r2, o3) : biasPiece;
        const int* np1 = nbr + (size_t)(p0 + 64) * 3;
        nx0 = __builtin_nontemporal_load(np1);
        nx1 = __builtin_nontemporal_load(np1 + 1);
        nx2 = __builtin_nontemporal_load(np1 + 2);
    }

    #pragma unroll
    for (int it = 0; it < ITERS; it++) {
        const size_t row = rowBase + (size_t)(p0 + it * 64);
        const float* yr = Yin + row * DTOT;

        // issue this iter's own-row loads (nontemporal: no reuse, keep L2 for mirror)
        f32x4 own = __builtin_nontemporal_load((const f32x4*)yr + q);
        f32x4 ownDA = {0.f, 0.f, 0.f, 0.f};
        if (q == 0) ownDA = __builtin_nontemporal_load((const f32x4*)(yr + 16));

        // issue next iter's gather from already-resident indices
        if (it + 1 < ITERS) {
            const char* r0 = MinB + (size_t)nx0 * MROW;
            const char* r1 = MinB + (size_t)nx1 * MROW;
            const char* r2 = MinB + (size_t)nx2 * MROW;
            gn0 = ldpiece(r0, r1, r2, o0);
            gn1 = ldpiece(r0, r1, r2, o1);
            gn2 = ldpiece(r0, r1, r2, o2);
            gn3 = (o3 < 120) ? ldpiece(r0, r1, r2, o3) : biasPiece;
        }
        // issue nbr idx for it+2
        if (it + 2 < ITERS) {
            const int* np = nbr + (size_t)(p0 + (it + 2) * 64) * 3;
            ny0 = __builtin_nontemporal_load(np);
            ny1 = __builtin_nontemporal_load(np + 1);
            ny2 = __builtin_nontemporal_load(np + 2);
        }

        // assemble B-fragments for layer 1: B[k][n=point l15], k=ks*32+q*8+j
        u32x4 u0 = { gc0.x, gc0.y, gc1.x, gc1.y };
        u32x4 u1 = { gc2.x, gc2.y, gc3.x, gc3.y };
        short8 zb0 = __builtin_bit_cast(short8, u0);
        short8 zb1 = __builtin_bit_cast(short8, u1);

        // ---- layer 1: D[hidden][point] = W1^T x Zf^T (+b1 via k=60 fold) ----
        #pragma unroll
        for (int nt = 0; nt < 8; nt++) {
            f32x4 acc = { 0.f, 0.f, 0.f, 0.f };
            acc = __builtin_amdgcn_mfma_f32_16x16x32_bf16(B1f[nt][0], zb0, acc, 0, 0, 0);
            acc = __builtin_amdgcn_mfma_f32_16x16x32_bf16(B1f[nt][1], zb1, acc, 0, 0, 0);
            // lane holds hidden nt*16 + q*4 + r for point l15 -> 4 consecutive -> b64 store
            u32x2 hw;
            hw.x = pack2(tanh_fast(acc[0]), tanh_fast(acc[1]));
            hw.y = pack2(tanh_fast(acc[2]), tanh_fast(acc[3]));
            *(u32x2*)((char*)hrow + l15 * 272 + nt * 32 + q * 8) = hw;
        }

        // ---- layer 2: E[d][point] = (DT*W2)^T x h^T ----
        f32x4 acc2 = acc2init;
        #pragma unroll
        for (int ks = 0; ks < 4; ks++) {
            short8 hb = *(const short8*)((const char*)hrow + l15 * 272 + ks * 64 + q * 16);
            acc2 = __builtin_amdgcn_mfma_f32_16x16x32_bf16(W2f[ks], hb, acc2, 0, 0, 0);
        }

        // ---- epilogue: lane owns point l15 (this iter), channels q*4..q*4+3 ----
        own.x += acc2[0]; own.y += acc2[1]; own.z += acc2[2]; own.w += acc2[3];
        float* yw = Yout + row * DTOT;
        __builtin_nontemporal_store(own, (f32x4*)yw + q);
        char* mrow = MoutB + (size_t)(p0 + it * 64) * MROW;
        u32x2 mw; mw.x = pack2(own.x, own.y); mw.y = pack2(own.z, own.w);
        *(u32x2*)(mrow + q * 8) = mw;
        if (q == 0) {
            __builtin_nontemporal_store(ownDA, (f32x4*)(yw + 16));
            u32x2 md; md.x = pack2(ownDA.x, ownDA.y); md.y = pack2(ownDA.z, ownDA.w);
            *(u32x2*)(mrow + 32) = md;
        }

        // rotate pipeline
        gc0 = gn0; gc1 = gn1; gc2 = gn2; gc3 = gn3;
        nx0 = ny0; nx1 = ny1; nx2 = ny2;
    }
}

// inputs (fp32) -> bf16 mirror, fully coalesced (8B out per 16B in)
__global__ __launch_bounds__(256) void build_mirror(
    const f32x4* __restrict__ in, u32x2* __restrict__ out, int n4)
{
    int i = blockIdx.x * 256 + threadIdx.x;
    if (i < n4) {
        f32x4 v = in[i];
        u32x2 o; o.x = pack2(v.x, v.y); o.y = pack2(v.z, v.w);
        out[i] = o;
    }
}

extern "C" void kernel_launch(void* const* d_in, const int* in_sizes, int n_in,
                              void* d_out, int out_size, void* d_ws, size_t ws_size,
                              hipStream_t stream) {
    const float* inputs = (const float*)d_in[0];
    const int*   nbr    = (const int*)  d_in[1];
    const float* W1     = (const float*)d_in[2];
    const float* b1     = (const float*)d_in[3];
    const float* W2     = (const float*)d_in[4];
    const float* b2     = (const float*)d_in[5];
    float* out = (float*)d_out;

    const size_t MBYTES = (size_t)B_DIM * NPTS * MROW;      // 26.2 MB
    unsigned short* M0 = (unsigned short*)d_ws;
    unsigned short* M1 = (unsigned short*)((char*)d_ws + MBYTES);

    const int n4 = B_DIM * NPTS * DTOT / 4;                 // 3,276,800
    build_mirror<<<n4 / 256, 256, 0, stream>>>((const f32x4*)inputs, (u32x2*)M0, n4);

    const dim3 grid(GRID), block(BLOCK);
    // step 1: read inputs, write out (+M1); steps 2-4: in-place on out, mirrors ping-pong
    neural_step_mfma<<<grid, block, 0, stream>>>(inputs, out, M0, M1, nbr, W1, b1, W2, b2);
    neural_step_mfma<<<grid, block, 0, stream>>>(out,    out, M1, M0, nbr, W1, b1, W2, b2);
    neural_step_mfma<<<grid, block, 0, stream>>>(out,    out, M0, M1, nbr, W1, b1, W2, b2);
    neural_step_mfma<<<grid, block, 0, stream>>>(out,    out, M1, M0, nbr, W1, b1, W2, b2);
}

// Round 6
// 370.203 us; speedup vs baseline: 1.0829x; 1.0829x over previous
//
#include <hip/hip_runtime.h>

// Problem constants
#define B_DIM 8
#define NPTS  81920
#define DTOT  20          // DL + DA
#define DT_STEP 0.1f

#define BLOCK 256
#define GRID  2560        // 10 blocks/CU queued; ~6 resident by LDS/VGPR
#define ITERS 4           // GRID/8 * ITERS * 64 = 81920 points per batch
#define MROW  40          // mirror row bytes (20 bf16)

typedef __attribute__((ext_vector_type(8))) short short8;   // 8 bf16 (4 VGPRs)
typedef __attribute__((ext_vector_type(4))) float f32x4;    // MFMA acc / NT-able vec
typedef __attribute__((ext_vector_type(2))) unsigned u32x2; // 8B vec
typedef __attribute__((ext_vector_type(4))) unsigned u32x4; // 16B dword glue
typedef __attribute__((ext_vector_type(2))) short short2v;

// ---- LDS ----
// phase 0: W1T [0,18432): 128 rows x 72 shorts (k=60 holds b1, 61..63 zero)
//          W2T [18432,22784): 16 rows x 136 shorts (pre-scaled by DT)
// loop:    h   [0,17408): per-wave 16 x 136 shorts (272 B rows) — wave-private
#define W2T_BASE 18432
#define SMEM_BYTES 22784

__device__ __forceinline__ unsigned short f2bf(float f) {
    unsigned u = __builtin_bit_cast(unsigned, f);
    u += 0x7FFFu + ((u >> 16) & 1u);           // RNE
    return (unsigned short)(u >> 16);
}
#if __has_builtin(__builtin_amdgcn_cvt_pk_bf16_f32)
__device__ __forceinline__ unsigned pack2(float a, float b) {
    short2v p = __builtin_amdgcn_cvt_pk_bf16_f32(a, b);
    return __builtin_bit_cast(unsigned, p);
}
#else
__device__ __forceinline__ unsigned pack2(float a, float b) {
    return (unsigned)f2bf(a) | ((unsigned)f2bf(b) << 16);
}
#endif
// tanh(x) = 1 - 2/(e^{2x}+1); e^{2x} = 2^(x*2/ln2). Inf-safe: exp2(+inf)->inf,
// rcp(inf)=0 -> 1; exp2(-inf)->0 -> 1-2 = -1. 5 VALU ops, no clamp.
__device__ __forceinline__ float tanh_fast(float x) {
    float e = __builtin_amdgcn_exp2f(x * 2.885390082f);
    float r = __builtin_amdgcn_rcpf(1.0f + e);
    return 1.0f - 2.0f * r;
}
// select an 8B piece of the 120B concat of 3 mirror rows (o multiple of 8, o<120)
__device__ __forceinline__ u32x2 ldpiece(const char* r0, const char* r1,
                                         const char* r2, int o) {
    const char* p = r0 + o;
    if (o >= 40) p = r1 + (o - 40);
    if (o >= 80) p = r2 + (o - 80);
    return *(const u32x2*)p;
}

__global__ __launch_bounds__(BLOCK, 3) void neural_step_mfma(
    const float* __restrict__ Yin, float* __restrict__ Yout,
    const unsigned short* __restrict__ Min,   // bf16 mirror of Yin
    unsigned short* __restrict__ Mout,        // bf16 mirror of Yout (written here)
    const int*   __restrict__ nbr,
    const float* __restrict__ W1, const float* __restrict__ b1,
    const float* __restrict__ W2, const float* __restrict__ b2)
{
    __shared__ __align__(16) char smem[SMEM_BYTES];
    const int t = threadIdx.x;

    // ---- phase 0: stage W1^T (+b1 fold) and DT*W2^T as bf16 ----
    unsigned short* sW1T = (unsigned short*)smem;
    for (int f = t; f < 60 * 128; f += BLOCK) {      // W1[k][n] -> sW1T[n][k]
        int k = f >> 7, n = f & 127;
        sW1T[n * 72 + k] = f2bf(W1[f]);
    }
    if (t < 128) {                                    // bias fold at k=60; pad 61..63
        sW1T[t * 72 + 60] = f2bf(b1[t]);
        sW1T[t * 72 + 61] = 0; sW1T[t * 72 + 62] = 0; sW1T[t * 72 + 63] = 0;
    }
    unsigned short* sW2T = (unsigned short*)(smem + W2T_BASE);
    for (int f = t; f < 128 * 16; f += BLOCK) {      // DT*W2[k][d] -> sW2T[d][k]
        int k = f >> 4, d = f & 15;
        sW2T[d * 136 + k] = f2bf(DT_STEP * W2[f]);
    }
    __syncthreads();

    const int lane = t & 63, w = t >> 6;
    const int l15 = lane & 15, q = lane >> 4;

    // W1 A-fragments: A[m=hidden nt*16+l15][k=ks*32+q*8+j]
    short8 B1f[8][2];
    #pragma unroll
    for (int nt = 0; nt < 8; nt++)
        #pragma unroll
        for (int ks = 0; ks < 2; ks++)
            B1f[nt][ks] = *(const short8*)(sW1T + (nt * 16 + l15) * 72 + ks * 32 + q * 8);
    // W2^T A-fragments: A[d=l15][k=ks*32+q*8+j]
    short8 W2f[4];
    #pragma unroll
    for (int ks = 0; ks < 4; ks++)
        W2f[ks] = *(const short8*)(sW2T + l15 * 136 + ks * 32 + q * 8);
    const float b2a = b2[q * 4 + 0], b2b = b2[q * 4 + 1];
    const float b2c = b2[q * 4 + 2], b2d = b2[q * 4 + 3];
    const f32x4 acc2init = { DT_STEP * b2a, DT_STEP * b2b,
                             DT_STEP * b2c, DT_STEP * b2d };
    __syncthreads();   // weights in regs; LDS region reused for h tiles

    // ---- batch-per-XCD swizzle ----
    const int bk = blockIdx.x;
    const int bB = bk & 7;
    const int p0 = (bk >> 3) * (ITERS * 64) + w * 16 + l15;  // this lane's point, +it*64
    const char*  MinB  = (const char*)Min + (size_t)bB * NPTS * MROW;
    char*        MoutB = (char*)Mout      + (size_t)bB * NPTS * MROW;
    const size_t rowBase = (size_t)bB * NPTS;

    unsigned short* hrow = (unsigned short*)(smem + w * 4352);

    // per-lane concat offsets for the 4 gather pieces (8B each)
    const int o0 = q * 16, o1 = o0 + 8, o2 = 64 + q * 16, o3 = o2 + 8;  // o3==120 iff q==3
    const u32x2 biasPiece = { 0x00003F80u, 0u };                        // bf16 {1,0,0,0}

    // ---- software pipeline: nbr idx 2 ahead, gather 1 ahead ----
    int nx0, nx1, nx2, ny0 = 0, ny1 = 0, ny2 = 0;
    u32x2 gc0, gc1, gc2, gc3, gn0 = {0,0}, gn1 = {0,0}, gn2 = {0,0}, gn3 = {0,0};
    {
        const int* np = nbr + (size_t)p0 * 3;
        nx0 = __builtin_nontemporal_load(np);
        nx1 = __builtin_nontemporal_load(np + 1);
        nx2 = __builtin_nontemporal_load(np + 2);
        const char* r0 = MinB + (size_t)nx0 * MROW;
        const char* r1 = MinB + (size_t)nx1 * MROW;
        const char* r2 = MinB + (size_t)nx2 * MROW;
        gc0 = ldpiece(r0, r1, r2, o0);
        gc1 = ldpiece(r0, r1, r2, o1);
        gc2 = ldpiece(r0, r1, r2, o2);
        gc3 = (o3 < 120) ? ldpiece(r0, r1, r2, o3) : biasPiece;
        const int* np1 = nbr + (size_t)(p0 + 64) * 3;
        nx0 = __builtin_nontemporal_load(np1);
        nx1 = __builtin_nontemporal_load(np1 + 1);
        nx2 = __builtin_nontemporal_load(np1 + 2);
    }

    #pragma unroll
    for (int it = 0; it < ITERS; it++) {
        const size_t row = rowBase + (size_t)(p0 + it * 64);
        const float* yr = Yin + row * DTOT;

        // issue this iter's own-row loads (NT: no reuse, keep L2 for mirror)
        f32x4 own = __builtin_nontemporal_load((const f32x4*)yr + q);
        f32x4 ownDA = {0.f, 0.f, 0.f, 0.f};
        if (q == 0) ownDA = __builtin_nontemporal_load((const f32x4*)(yr + 16));

        // issue next iter's gather from already-resident indices
        if (it + 1 < ITERS) {
            const char* r0 = MinB + (size_t)nx0 * MROW;
            const char* r1 = MinB + (size_t)nx1 * MROW;
            const char* r2 = MinB + (size_t)nx2 * MROW;
            gn0 = ldpiece(r0, r1, r2, o0);
            gn1 = ldpiece(r0, r1, r2, o1);
            gn2 = ldpiece(r0, r1, r2, o2);
            gn3 = (o3 < 120) ? ldpiece(r0, r1, r2, o3) : biasPiece;
        }
        // issue nbr idx for it+2
        if (it + 2 < ITERS) {
            const int* np = nbr + (size_t)(p0 + (it + 2) * 64) * 3;
            ny0 = __builtin_nontemporal_load(np);
            ny1 = __builtin_nontemporal_load(np + 1);
            ny2 = __builtin_nontemporal_load(np + 2);
        }

        // assemble B-fragments for layer 1: B[k][n=point l15], k=ks*32+q*8+j
        u32x4 u0 = { gc0.x, gc0.y, gc1.x, gc1.y };
        u32x4 u1 = { gc2.x, gc2.y, gc3.x, gc3.y };
        short8 zb0 = __builtin_bit_cast(short8, u0);
        short8 zb1 = __builtin_bit_cast(short8, u1);

        // ---- layer 1: D[hidden][point] = W1^T x Zf^T (+b1 via k=60 fold) ----
        #pragma unroll
        for (int nt = 0; nt < 8; nt++) {
            f32x4 acc = { 0.f, 0.f, 0.f, 0.f };
            acc = __builtin_amdgcn_mfma_f32_16x16x32_bf16(B1f[nt][0], zb0, acc, 0, 0, 0);
            acc = __builtin_amdgcn_mfma_f32_16x16x32_bf16(B1f[nt][1], zb1, acc, 0, 0, 0);
            // lane holds hidden nt*16 + q*4 + r for point l15 -> 4 consecutive -> b64 store
            u32x2 hw;
            hw.x = pack2(tanh_fast(acc[0]), tanh_fast(acc[1]));
            hw.y = pack2(tanh_fast(acc[2]), tanh_fast(acc[3]));
            *(u32x2*)((char*)hrow + l15 * 272 + nt * 32 + q * 8) = hw;
        }

        // ---- layer 2: E[d][point] = (DT*W2)^T x h^T ----
        f32x4 acc2 = acc2init;
        #pragma unroll
        for (int ks = 0; ks < 4; ks++) {
            short8 hb = *(const short8*)((const char*)hrow + l15 * 272 + ks * 64 + q * 16);
            acc2 = __builtin_amdgcn_mfma_f32_16x16x32_bf16(W2f[ks], hb, acc2, 0, 0, 0);
        }

        // ---- epilogue: lane owns point l15 (this iter), channels q*4..q*4+3 ----
        own.x += acc2[0]; own.y += acc2[1]; own.z += acc2[2]; own.w += acc2[3];
        float* yw = Yout + row * DTOT;
        *((f32x4*)yw + q) = own;                          // regular store: L2 write-combine
        char* mrow = MoutB + (size_t)(p0 + it * 64) * MROW;
        u32x2 mw; mw.x = pack2(own.x, own.y); mw.y = pack2(own.z, own.w);
        *(u32x2*)(mrow + q * 8) = mw;
        if (q == 0) {
            *((f32x4*)(yw + 16)) = ownDA;
            u32x2 md; md.x = pack2(ownDA.x, ownDA.y); md.y = pack2(ownDA.z, ownDA.w);
            *(u32x2*)(mrow + 32) = md;
        }

        // rotate pipeline
        gc0 = gn0; gc1 = gn1; gc2 = gn2; gc3 = gn3;
        nx0 = ny0; nx1 = ny1; nx2 = ny2;
    }
}

// inputs (fp32) -> bf16 mirror, fully coalesced (8B out per 16B in)
__global__ __launch_bounds__(256) void build_mirror(
    const f32x4* __restrict__ in, u32x2* __restrict__ out, int n4)
{
    int i = blockIdx.x * 256 + threadIdx.x;
    if (i < n4) {
        f32x4 v = in[i];
        u32x2 o; o.x = pack2(v.x, v.y); o.y = pack2(v.z, v.w);
        out[i] = o;
    }
}

extern "C" void kernel_launch(void* const* d_in, const int* in_sizes, int n_in,
                              void* d_out, int out_size, void* d_ws, size_t ws_size,
                              hipStream_t stream) {
    const float* inputs = (const float*)d_in[0];
    const int*   nbr    = (const int*)  d_in[1];
    const float* W1     = (const float*)d_in[2];
    const float* b1     = (const float*)d_in[3];
    const float* W2     = (const float*)d_in[4];
    const float* b2     = (const float*)d_in[5];
    float* out = (float*)d_out;

    const size_t MBYTES = (size_t)B_DIM * NPTS * MROW;      // 26.2 MB
    unsigned short* M0 = (unsigned short*)d_ws;
    unsigned short* M1 = (unsigned short*)((char*)d_ws + MBYTES);

    const int n4 = B_DIM * NPTS * DTOT / 4;                 // 3,276,800
    build_mirror<<<n4 / 256, 256, 0, stream>>>((const f32x4*)inputs, (u32x2*)M0, n4);

    const dim3 grid(GRID), block(BLOCK);
    // step 1: read inputs, write out (+M1); steps 2-4: in-place on out, mirrors ping-pong
    neural_step_mfma<<<grid, block, 0, stream>>>(inputs, out, M0, M1, nbr, W1, b1, W2, b2);
    neural_step_mfma<<<grid, block, 0, stream>>>(out,    out, M1, M0, nbr, W1, b1, W2, b2);
    neural_step_mfma<<<grid, block, 0, stream>>>(out,    out, M0, M1, nbr, W1, b1, W2, b2);
    neural_step_mfma<<<grid, block, 0, stream>>>(out,    out, M1, M0, nbr, W1, b1, W2, b2);
}

// Round 7
// 362.051 us; speedup vs baseline: 1.1073x; 1.0225x over previous
//
#include <hip/hip_runtime.h>

// Problem constants
#define B_DIM 8
#define NPTS  81920
#define DTOT  20          // DL + DA
#define DT_STEP 0.1f

#define BLOCK 256
#define GRID  2560        // 10 blocks/CU queued
#define ITERS 4           // GRID/8 * ITERS * 64 = 81920 points per batch
#define MROW  40          // mirror row bytes (20 bf16)

typedef __attribute__((ext_vector_type(8))) short short8;   // 8 bf16 (4 VGPRs)
typedef __attribute__((ext_vector_type(4))) float f32x4;    // MFMA acc / NT-able vec
typedef __attribute__((ext_vector_type(2))) unsigned u32x2; // 8B vec
typedef __attribute__((ext_vector_type(4))) unsigned u32x4; // 16B dword glue
typedef __attribute__((ext_vector_type(2))) short short2v;

// ---- LDS: h tiles only, per-wave 16 x 136 shorts (272 B rows) ----
#define SMEM_BYTES 17408

// ---- ws layout ----
// [0, 26.2MB)      mirror M0
// [26.2, 52.4MB)   mirror M1
// [52.4MB, +21504) weight-fragment image: 21 frags x 64 lanes x 16 B
//   frag 0..15  = B1f[nt][ks] (f = nt*2+ks)
//   frag 16..19 = W2f[ks]
//   frag 20     = acc2init (f32x4 per lane)
#define NFRAG 21

__device__ __forceinline__ unsigned short f2bf(float f) {
    unsigned u = __builtin_bit_cast(unsigned, f);
    u += 0x7FFFu + ((u >> 16) & 1u);           // RNE
    return (unsigned short)(u >> 16);
}
#if __has_builtin(__builtin_amdgcn_cvt_pk_bf16_f32)
__device__ __forceinline__ unsigned pack2(float a, float b) {
    short2v p = __builtin_amdgcn_cvt_pk_bf16_f32(a, b);
    return __builtin_bit_cast(unsigned, p);
}
#else
__device__ __forceinline__ unsigned pack2(float a, float b) {
    return (unsigned)f2bf(a) | ((unsigned)f2bf(b) << 16);
}
#endif
// tanh(x) = 1 - 2/(e^{2x}+1). Inf-safe; 5 VALU ops.
__device__ __forceinline__ float tanh_fast(float x) {
    float e = __builtin_amdgcn_exp2f(x * 2.885390082f);
    float r = __builtin_amdgcn_rcpf(1.0f + e);
    return 1.0f - 2.0f * r;
}
// select an 8B piece of the 120B concat of 3 mirror rows (o multiple of 8, o<120)
__device__ __forceinline__ u32x2 ldpiece(const char* r0, const char* r1,
                                         const char* r2, int o) {
    const char* p = r0 + o;
    if (o >= 40) p = r1 + (o - 40);
    if (o >= 80) p = r2 + (o - 80);
    return *(const u32x2*)p;
}

// ---- one-time prep: bake per-lane MFMA fragments of W1 (+b1 fold), DT*W2, DT*b2 ----
__global__ __launch_bounds__(256) void prep_frags(
    const float* __restrict__ W1, const float* __restrict__ b1,
    const float* __restrict__ W2, const float* __restrict__ b2,
    char* __restrict__ img)
{
    const int t = threadIdx.x, lane = t & 63, g = t >> 6;
    const int l15 = lane & 15, q = lane >> 4;
    for (int f = g; f < NFRAG; f += 4) {
        char* dst = img + (f * 64 + lane) * 16;
        if (f < 16) {                       // B1f[nt][ks]: A[m=nt*16+l15][k=ks*32+q*8+j]
            const int nt = f >> 1, ks = f & 1, m = nt * 16 + l15;
            unsigned short v[8];
            #pragma unroll
            for (int j = 0; j < 8; j++) {
                const int k = ks * 32 + q * 8 + j;
                float x = (k < 60) ? W1[k * 128 + m] : (k == 60 ? b1[m] : 0.0f);
                v[j] = f2bf(x);
            }
            *(u32x4*)dst = *(const u32x4*)v;
        } else if (f < 20) {                // W2f[ks]: A[d=l15][k=ks*32+q*8+j], pre-scaled
            const int ks = f - 16;
            unsigned short v[8];
            #pragma unroll
            for (int j = 0; j < 8; j++) {
                const int k = ks * 32 + q * 8 + j;
                v[j] = f2bf(DT_STEP * W2[k * 16 + l15]);
            }
            *(u32x4*)dst = *(const u32x4*)v;
        } else {                            // acc2init: DT*b2[q*4+r]
            f32x4 a = { DT_STEP * b2[q * 4 + 0], DT_STEP * b2[q * 4 + 1],
                        DT_STEP * b2[q * 4 + 2], DT_STEP * b2[q * 4 + 3] };
            *(f32x4*)dst = a;
        }
    }
}

__global__ __launch_bounds__(BLOCK) void neural_step_mfma(
    const float* __restrict__ Yin, float* __restrict__ Yout,
    const unsigned short* __restrict__ Min,   // bf16 mirror of Yin
    unsigned short* __restrict__ Mout,        // bf16 mirror of Yout (written here)
    const int*   __restrict__ nbr,
    const char*  __restrict__ img)            // baked fragment image
{
    __shared__ __align__(16) char smem[SMEM_BYTES];
    const int t = threadIdx.x;
    const int lane = t & 63, w = t >> 6;
    const int l15 = lane & 15, q = lane >> 4;

    // ---- phase 0: 21 coalesced dwordx4 loads, no LDS, no barrier ----
    const short8* frg = (const short8*)img;
    short8 B1f[8][2];
    #pragma unroll
    for (int nt = 0; nt < 8; nt++)
        #pragma unroll
        for (int ks = 0; ks < 2; ks++)
            B1f[nt][ks] = frg[(nt * 2 + ks) * 64 + lane];
    short8 W2f[4];
    #pragma unroll
    for (int ks = 0; ks < 4; ks++)
        W2f[ks] = frg[(16 + ks) * 64 + lane];
    const f32x4 acc2init = ((const f32x4*)img)[20 * 64 + lane];

    // ---- batch-per-XCD swizzle ----
    const int bk = blockIdx.x;
    const int bB = bk & 7;
    const int p0 = (bk >> 3) * (ITERS * 64) + w * 16 + l15;  // this lane's point, +it*64
    const char*  MinB  = (const char*)Min + (size_t)bB * NPTS * MROW;
    char*        MoutB = (char*)Mout      + (size_t)bB * NPTS * MROW;
    const size_t rowBase = (size_t)bB * NPTS;

    unsigned short* hrow = (unsigned short*)(smem + w * 4352);

    // per-lane concat offsets for the 4 gather pieces (8B each)
    const int o0 = q * 16, o1 = o0 + 8, o2 = 64 + q * 16, o3 = o2 + 8;  // o3==120 iff q==3
    const u32x2 biasPiece = { 0x00003F80u, 0u };                        // bf16 {1,0,0,0}

    // ---- software pipeline: nbr idx 2 ahead, gather 1 ahead ----
    int nx0, nx1, nx2, ny0 = 0, ny1 = 0, ny2 = 0;
    u32x2 gc0, gc1, gc2, gc3, gn0 = {0,0}, gn1 = {0,0}, gn2 = {0,0}, gn3 = {0,0};
    {
        const int* np = nbr + (size_t)p0 * 3;
        nx0 = __builtin_nontemporal_load(np);
        nx1 = __builtin_nontemporal_load(np + 1);
        nx2 = __builtin_nontemporal_load(np + 2);
        const char* r0 = MinB + (size_t)nx0 * MROW;
        const char* r1 = MinB + (size_t)nx1 * MROW;
        const char* r2 = MinB + (size_t)nx2 * MROW;
        gc0 = ldpiece(r0, r1, r2, o0);
        gc1 = ldpiece(r0, r1, r2, o1);
        gc2 = ldpiece(r0, r1, r2, o2);
        gc3 = (o3 < 120) ? ldpiece(r0, r1, r2, o3) : biasPiece;
        const int* np1 = nbr + (size_t)(p0 + 64) * 3;
        nx0 = __builtin_nontemporal_load(np1);
        nx1 = __builtin_nontemporal_load(np1 + 1);
        nx2 = __builtin_nontemporal_load(np1 + 2);
    }

    #pragma unroll
    for (int it = 0; it < ITERS; it++) {
        const size_t row = rowBase + (size_t)(p0 + it * 64);
        const float* yr = Yin + row * DTOT;

        // issue this iter's own-row loads (NT: no reuse, keep L2 for mirror)
        f32x4 own = __builtin_nontemporal_load((const f32x4*)yr + q);
        f32x4 ownDA = {0.f, 0.f, 0.f, 0.f};
        if (q == 0) ownDA = __builtin_nontemporal_load((const f32x4*)(yr + 16));

        // issue next iter's gather from already-resident indices
        if (it + 1 < ITERS) {
            const char* r0 = MinB + (size_t)nx0 * MROW;
            const char* r1 = MinB + (size_t)nx1 * MROW;
            const char* r2 = MinB + (size_t)nx2 * MROW;
            gn0 = ldpiece(r0, r1, r2, o0);
            gn1 = ldpiece(r0, r1, r2, o1);
            gn2 = ldpiece(r0, r1, r2, o2);
            gn3 = (o3 < 120) ? ldpiece(r0, r1, r2, o3) : biasPiece;
        }
        // issue nbr idx for it+2
        if (it + 2 < ITERS) {
            const int* np = nbr + (size_t)(p0 + (it + 2) * 64) * 3;
            ny0 = __builtin_nontemporal_load(np);
            ny1 = __builtin_nontemporal_load(np + 1);
            ny2 = __builtin_nontemporal_load(np + 2);
        }

        // assemble B-fragments for layer 1: B[k][n=point l15], k=ks*32+q*8+j
        u32x4 u0 = { gc0.x, gc0.y, gc1.x, gc1.y };
        u32x4 u1 = { gc2.x, gc2.y, gc3.x, gc3.y };
        short8 zb0 = __builtin_bit_cast(short8, u0);
        short8 zb1 = __builtin_bit_cast(short8, u1);

        // ---- layer 1: D[hidden][point] = W1^T x Zf^T (+b1 via k=60 fold) ----
        #pragma unroll
        for (int nt = 0; nt < 8; nt++) {
            f32x4 acc = { 0.f, 0.f, 0.f, 0.f };
            acc = __builtin_amdgcn_mfma_f32_16x16x32_bf16(B1f[nt][0], zb0, acc, 0, 0, 0);
            acc = __builtin_amdgcn_mfma_f32_16x16x32_bf16(B1f[nt][1], zb1, acc, 0, 0, 0);
            // lane holds hidden nt*16 + q*4 + r for point l15 -> 4 consecutive -> b64 store
            u32x2 hw;
            hw.x = pack2(tanh_fast(acc[0]), tanh_fast(acc[1]));
            hw.y = pack2(tanh_fast(acc[2]), tanh_fast(acc[3]));
            *(u32x2*)((char*)hrow + l15 * 272 + nt * 32 + q * 8) = hw;
        }

        // ---- layer 2: E[d][point] = (DT*W2)^T x h^T ----
        f32x4 acc2 = acc2init;
        #pragma unroll
        for (int ks = 0; ks < 4; ks++) {
            short8 hb = *(const short8*)((const char*)hrow + l15 * 272 + ks * 64 + q * 16);
            acc2 = __builtin_amdgcn_mfma_f32_16x16x32_bf16(W2f[ks], hb, acc2, 0, 0, 0);
        }

        // ---- epilogue: lane owns point l15 (this iter), channels q*4..q*4+3 ----
        own.x += acc2[0]; own.y += acc2[1]; own.z += acc2[2]; own.w += acc2[3];
        float* yw = Yout + row * DTOT;
        *((f32x4*)yw + q) = own;                          // regular store: L2 write-combine
        char* mrow = MoutB + (size_t)(p0 + it * 64) * MROW;
        u32x2 mw; mw.x = pack2(own.x, own.y); mw.y = pack2(own.z, own.w);
        *(u32x2*)(mrow + q * 8) = mw;
        if (q == 0) {
            *((f32x4*)(yw + 16)) = ownDA;
            u32x2 md; md.x = pack2(ownDA.x, ownDA.y); md.y = pack2(ownDA.z, ownDA.w);
            *(u32x2*)(mrow + 32) = md;
        }

        // rotate pipeline
        gc0 = gn0; gc1 = gn1; gc2 = gn2; gc3 = gn3;
        nx0 = ny0; nx1 = ny1; nx2 = ny2;
    }
}

// inputs (fp32) -> bf16 mirror, fully coalesced (8B out per 16B in)
__global__ __launch_bounds__(256) void build_mirror(
    const f32x4* __restrict__ in, u32x2* __restrict__ out, int n4)
{
    int i = blockIdx.x * 256 + threadIdx.x;
    if (i < n4) {
        f32x4 v = in[i];
        u32x2 o; o.x = pack2(v.x, v.y); o.y = pack2(v.z, v.w);
        out[i] = o;
    }
}

extern "C" void kernel_launch(void* const* d_in, const int* in_sizes, int n_in,
                              void* d_out, int out_size, void* d_ws, size_t ws_size,
                              hipStream_t stream) {
    const float* inputs = (const float*)d_in[0];
    const int*   nbr    = (const int*)  d_in[1];
    const float* W1     = (const float*)d_in[2];
    const float* b1     = (const float*)d_in[3];
    const float* W2     = (const float*)d_in[4];
    const float* b2     = (const float*)d_in[5];
    float* out = (float*)d_out;

    const size_t MBYTES = (size_t)B_DIM * NPTS * MROW;      // 26.2 MB
    unsigned short* M0 = (unsigned short*)d_ws;
    unsigned short* M1 = (unsigned short*)((char*)d_ws + MBYTES);
    char*           FI = (char*)d_ws + 2 * MBYTES;          // 21.5 KB fragment image

    const int n4 = B_DIM * NPTS * DTOT / 4;                 // 3,276,800
    build_mirror<<<n4 / 256, 256, 0, stream>>>((const f32x4*)inputs, (u32x2*)M0, n4);
    prep_frags<<<1, 256, 0, stream>>>(W1, b1, W2, b2, FI);

    const dim3 grid(GRID), block(BLOCK);
    // step 1: read inputs, write out (+M1); steps 2-4: in-place on out, mirrors ping-pong
    neural_step_mfma<<<grid, block, 0, stream>>>(inputs, out, M0, M1, nbr, FI);
    neural_step_mfma<<<grid, block, 0, stream>>>(out,    out, M1, M0, nbr, FI);
    neural_step_mfma<<<grid, block, 0, stream>>>(out,    out, M0, M1, nbr, FI);
    neural_step_mfma<<<grid, block, 0, stream>>>(out,    out, M1, M0, nbr, FI);
}